// Round 8
// baseline (115.009 us; speedup 1.0000x reference)
//
#include <hip/hip_runtime.h>
#include <math.h>

// Problem constants (from reference)
#define NSAMP 16
#define NPTS  512
#define MDIM  4096     // 64*64 grid
#define NIT   100

// 16x16 window (rows rn-7..rn+8, cols cn-7..cn+8), 4 cells/lane for a wave.
// Support analysis (R4/R5/R6-validated at +-7): z = v - 0.1*d^2; worst-case
// pit rim ~44px, mass-significant tail to ~47px < 52px worst-case reach;
// beyond-window cells hold e^-84-level mass. All 256 cells valid (no mask).
#define R0MAX 48

// parity swizzle: odd rows XOR col by 16 -> window cols hit 16 banks, odd
// rows the complementary 16 -> 2 lanes/bank = free (m136). Row stride 64.
__device__ __forceinline__ int swz(int r, int c) {
  return r * 64 + (c ^ ((r & 1) << 4));
}

// ---------------- Threefry-2x32 (JAX-exact, partitionable path; R0-verified)
__device__ __forceinline__ void tf2x32(unsigned k0, unsigned k1,
                                       unsigned c0, unsigned c1,
                                       unsigned &o0, unsigned &o1)
{
  unsigned ks2 = k0 ^ k1 ^ 0x1BD11BDAu;
  unsigned x0 = c0 + k0, x1 = c1 + k1;
#define ROT(r) x0 += x1; x1 = (x1 << (r)) | (x1 >> (32 - (r))); x1 ^= x0;
#define G0 ROT(13) ROT(15) ROT(26) ROT(6)
#define G1 ROT(17) ROT(29) ROT(16) ROT(24)
  G0 x0 += k1;  x1 += ks2 + 1u;
  G1 x0 += ks2; x1 += k0  + 2u;
  G0 x0 += k0;  x1 += k1  + 3u;
  G1 x0 += k1;  x1 += ks2 + 4u;
  G0 x0 += ks2; x1 += k0  + 5u;
#undef G0
#undef G1
#undef ROT
  o0 = x0; o1 = x1;
}

__device__ __forceinline__ int rand_idx(int f)
{
  unsigned ka, kb, w0, w1;
  tf2x32(0u, 1u, 0u, 1u, ka, kb);            // split(key(1))[1] — folded
  tf2x32(ka, kb, 0u, (unsigned)f, w0, w1);   // random_bits elem f
  return (int)((w0 ^ w1) & 511u);
}

// ---------------- wave64 reductions via DPP (R1-R6-verified) ----------------
template<int CTRL>
__device__ __forceinline__ float dpp_mv(float v, float id)
{
  return __int_as_float(__builtin_amdgcn_update_dpp(
      __float_as_int(id), __float_as_int(v), CTRL, 0xF, 0xF, false));
}

__device__ __forceinline__ float waveMax(float v)
{
  v = fmaxf(v, dpp_mv<0x111>(v, -INFINITY));
  v = fmaxf(v, dpp_mv<0x112>(v, -INFINITY));
  v = fmaxf(v, dpp_mv<0x114>(v, -INFINITY));
  v = fmaxf(v, dpp_mv<0x118>(v, -INFINITY));
  v = fmaxf(v, dpp_mv<0x142>(v, -INFINITY));
  v = fmaxf(v, dpp_mv<0x143>(v, -INFINITY));
  return __int_as_float(__builtin_amdgcn_readlane(__float_as_int(v), 63));
}

__device__ __forceinline__ float waveSum(float v)
{
  v += dpp_mv<0x111>(v, 0.0f);
  v += dpp_mv<0x112>(v, 0.0f);
  v += dpp_mv<0x114>(v, 0.0f);
  v += dpp_mv<0x118>(v, 0.0f);
  v += dpp_mv<0x142>(v, 0.0f);
  v += dpp_mv<0x143>(v, 0.0f);
  return __int_as_float(__builtin_amdgcn_readlane(__float_as_int(v), 63));
}

// ---------------- Fused kernel: scan (wave 0) + rows (16 waves) -------------
// Phase 1 state (R6-validated algebra): v = 0.1*cur + lnb = D + b*A lazily;
// avacc = sum(Pk*khi), Pk = step1*(101-k)/100; beta = 10*(b*SP - avacc);
// w = 0.1*beta + lnb. loss: analytically 0 (R6-validated, absmax 2.5e-6).
// Phase 2: per point, wd_row = (1/512)*sum(e*d^2)/sum(e) over the window.
__global__ __launch_bounds__(1024) void kern_fused(
    const float *__restrict__ normed, const float *__restrict__ pts,
    float *__restrict__ out)
{
  const int s = blockIdx.x;
  const int t = threadIdx.x;
  const int v = t >> 6;            // wave 0..15
  const int L = t & 63;

  __shared__ float2 dav[MDIM];     // 32 KB: (D, avacc), swizzled
  __shared__ float  barr[MDIM];    // 16 KB: b, becomes w[] after phase 1
  __shared__ float2 pts2[NPTS];    // 4 KB
  __shared__ float2 sampk[NIT];    // 800 B
  __shared__ float  wdred[16];

  // ---- init (all 16 waves; wave v owns grid rows 4v..4v+3) ----
  #pragma unroll
  for (int l = 0; l < 4; ++l) {
    const int r = 4 * v + l;
    const float bv = normed[s * MDIM + r * 64 + L];
    const int idx = swz(r, L);
    dav[idx]  = make_float2(__logf(bv), 0.0f);   // v0 = lnb
    barr[idx] = bv;
  }
  if (t < NPTS) pts2[t] = ((const float2 *)pts)[s * NPTS + t];
  if (t < NIT) {
    const int idx = rand_idx(s * NIT + t);
    sampk[t] = ((const float2 *)pts)[s * NPTS + idx];
  }
  __syncthreads();

  const int rbase = L >> 4;        // 0..3 (window row within quad)
  const int cbase = L & 15;        // window col

  // ---- phase 1: 100-iter ASGD scan, wave 0 only (others wait) ----
  if (v == 0) {
    float A = 0.0f, SP = 0.0f;
    for (int k = 1; k <= NIT; ++k) {
      const float2 p = sampk[k - 1];
      const float x = p.x, y = p.y;
      const int rn = (int)floorf((y - 4.0f) * 0.125f + 0.5f);
      const int cn = (int)floorf((x - 4.0f) * 0.125f + 0.5f);
      int r0 = rn - 7; r0 = r0 < 0 ? 0 : (r0 > R0MAX ? R0MAX : r0);
      int c0 = cn - 7; c0 = c0 < 0 ? 0 : (c0 > R0MAX ? R0MAX : c0);
      const int rl = r0 + rbase;                 // lane row (q adds 4)
      const int cl = c0 + cbase;                 // lane col (const over q)
      const int j0 = swz(rl, cl);                // q stride = 256 (parity const)

      const float kf    = (float)k;
      const float step1 = 512.0f * __builtin_amdgcn_rsqf(kf);   // 0.1*lr/sqrt(k)
      const float Pk    = step1 * (0.01f * (101.0f - kf));

      float2 c4[4]; float bv4[4];
      #pragma unroll
      for (int q = 0; q < 4; ++q) {
        c4[q]  = dav[j0 + 256 * q];
        bv4[q] = barr[j0 + 256 * q];
      }
      const float dx  = x - (float)(8 * cl + 4);
      const float dxx = dx * dx;
      const float ty  = y - (float)(8 * rl + 4); // dy_q = ty - 32q
      float z[4];
      #pragma unroll
      for (int q = 0; q < 4; ++q) {
        const float dy = ty - (float)(32 * q);
        const float g  = fmaf(dy, dy, dxx);
        z[q] = fmaf(g, -0.1f, fmaf(bv4[q], A, c4[q].x));
      }
      const float m = waveMax(fmaxf(fmaxf(z[0], z[1]), fmaxf(z[2], z[3])));
      float e[4], ss = 0.0f;
      #pragma unroll
      for (int q = 0; q < 4; ++q) { e[q] = __expf(z[q] - m); ss += e[q]; }
      const float S    = waveSum(ss);            // >= 1 (max cell e=1)
      const float invS = __builtin_amdgcn_rcpf(S);
      const float cD = step1 * invS, cA = Pk * invS;
      #pragma unroll
      for (int q = 0; q < 4; ++q) {
        c4[q].x = fmaf(-cD, e[q], c4[q].x);
        c4[q].y = fmaf(cA, e[q], c4[q].y);
        dav[j0 + 256 * q] = c4[q];
      }
      A += step1;
      SP += Pk;
    }
    // epilogue: overwrite barr with w[] (in-wave DS order, no barrier); ot
    float p_ot = 0.0f;
    for (int r = 0; r < 64; ++r) {
      const int idx = swz(r, L);                 // per-row lane permutation: ok
      const float2 cd = dav[idx];
      const float bb  = barr[idx];
      const float tt  = fmaf(bb, SP, -cd.y);     // 0.1*beta
      barr[idx] = tt + __logf(bb);               // w = 0.1*beta + lnb
      p_ot = fmaf(bb, 10.0f * tt, p_ot);
    }
    const float ot = waveSum(p_ot);
    if (L == 0) atomicAdd(&out[2], ot);          // 16 blocks: no contention
  }
  __syncthreads();                               // barr now holds w[]

  // ---- phase 2: windowed per-point logsumexp + wd (all 16 waves) ----
  float wdacc = 0.0f;
  for (int pi = 0; pi < 32; ++pi) {
    const int p = 32 * v + pi;
    const float2 pt = pts2[p];                   // LDS broadcast
    const float x = pt.x, y = pt.y;
    const int rn = (int)floorf((y - 4.0f) * 0.125f + 0.5f);
    const int cn = (int)floorf((x - 4.0f) * 0.125f + 0.5f);
    int r0 = rn - 7; r0 = r0 < 0 ? 0 : (r0 > R0MAX ? R0MAX : r0);
    int c0 = cn - 7; c0 = c0 < 0 ? 0 : (c0 > R0MAX ? R0MAX : c0);
    const int rl = r0 + rbase;
    const int cl = c0 + cbase;
    const int j0 = swz(rl, cl);

    const float dx  = x - (float)(8 * cl + 4);
    const float dxx = dx * dx;
    const float ty  = y - (float)(8 * rl + 4);
    float z[4], q2[4];
    #pragma unroll
    for (int q = 0; q < 4; ++q) {
      const float wv = barr[j0 + 256 * q];
      const float dy = ty - (float)(32 * q);
      q2[q] = fmaf(dy, dy, dxx);
      z[q]  = fmaf(q2[q], -0.1f, wv);
    }
    const float m = waveMax(fmaxf(fmaxf(z[0], z[1]), fmaxf(z[2], z[3])));
    float pe = 0.0f, pq = 0.0f;
    #pragma unroll
    for (int q = 0; q < 4; ++q) {
      const float e = __expf(z[q] - m);
      pe += e;
      pq = fmaf(e, q2[q], pq);
    }
    pe = waveSum(pe);
    pq = waveSum(pq);
    wdacc += pq / pe;                            // alpha shift cancels exactly
  }
  if (L == 0) wdred[v] = wdacc;
  __syncthreads();
  if (t == 0) {
    float wd = 0.0f;
    #pragma unroll
    for (int i = 0; i < 16; ++i) wd += wdred[i];
    atomicAdd(&out[1], wd * (1.0f / 512.0f));
    // out[0] (loss): analytically exact 0; memset provides it.
  }
}

extern "C" void kernel_launch(void* const* d_in, const int* in_sizes, int n_in,
                              void* d_out, int out_size, void* d_ws, size_t ws_size,
                              hipStream_t stream)
{
  (void)in_sizes; (void)n_in; (void)out_size; (void)d_ws; (void)ws_size;
  const float *normed = (const float *)d_in[0];
  const float *pts    = (const float *)d_in[2];
  float *out = (float *)d_out;

  hipMemsetAsync(out, 0, 3 * sizeof(float), stream);
  kern_fused<<<dim3(NSAMP), dim3(1024), 0, stream>>>(normed, pts, out);
}

// Round 9
// 110.769 us; speedup vs baseline: 1.0383x; 1.0383x over previous
//
#include <hip/hip_runtime.h>
#include <math.h>

// Problem constants (from reference)
#define NSAMP 16
#define NPTS  512
#define MDIM  4096     // 64*64 grid
#define NIT   100

// 16x16 window (rows rn-7..rn+8, cols cn-7..cn+8), 4 cells/lane for a wave.
// Support analysis (R4-R7-validated): beyond-window cells hold e^-80-level
// mass; absmax 2.5e-6 across four rounds. All 256 cells valid (no mask).
#define R0MAX 48

// parity swizzle: odd rows XOR col by 16 -> window cols hit 16 banks, odd
// rows the complementary 16 -> ~2 lanes/bank (R7: conflicts 75k -> 2k).
__device__ __forceinline__ int swz(int r, int c) {
  return r * 64 + (c ^ ((r & 1) << 4));
}

// ---------------- Threefry-2x32 (JAX-exact, partitionable path; R0-verified)
__device__ __forceinline__ void tf2x32(unsigned k0, unsigned k1,
                                       unsigned c0, unsigned c1,
                                       unsigned &o0, unsigned &o1)
{
  unsigned ks2 = k0 ^ k1 ^ 0x1BD11BDAu;
  unsigned x0 = c0 + k0, x1 = c1 + k1;
#define ROT(r) x0 += x1; x1 = (x1 << (r)) | (x1 >> (32 - (r))); x1 ^= x0;
#define G0 ROT(13) ROT(15) ROT(26) ROT(6)
#define G1 ROT(17) ROT(29) ROT(16) ROT(24)
  G0 x0 += k1;  x1 += ks2 + 1u;
  G1 x0 += ks2; x1 += k0  + 2u;
  G0 x0 += k0;  x1 += k1  + 3u;
  G1 x0 += k1;  x1 += ks2 + 4u;
  G0 x0 += ks2; x1 += k0  + 5u;
#undef G0
#undef G1
#undef ROT
  o0 = x0; o1 = x1;
}

__device__ __forceinline__ int rand_idx(int f)
{
  unsigned ka, kb, w0, w1;
  tf2x32(0u, 1u, 0u, 1u, ka, kb);            // split(key(1))[1] — folded
  tf2x32(ka, kb, 0u, (unsigned)f, w0, w1);   // random_bits elem f
  return (int)((w0 ^ w1) & 511u);
}

// ---------------- wave64 reductions via DPP (R1-R7-verified) ----------------
template<int CTRL>
__device__ __forceinline__ float dpp_mv(float v, float id)
{
  return __int_as_float(__builtin_amdgcn_update_dpp(
      __float_as_int(id), __float_as_int(v), CTRL, 0xF, 0xF, false));
}

__device__ __forceinline__ float waveMax(float v)
{
  v = fmaxf(v, dpp_mv<0x111>(v, -INFINITY));
  v = fmaxf(v, dpp_mv<0x112>(v, -INFINITY));
  v = fmaxf(v, dpp_mv<0x114>(v, -INFINITY));
  v = fmaxf(v, dpp_mv<0x118>(v, -INFINITY));
  v = fmaxf(v, dpp_mv<0x142>(v, -INFINITY));
  v = fmaxf(v, dpp_mv<0x143>(v, -INFINITY));
  return __int_as_float(__builtin_amdgcn_readlane(__float_as_int(v), 63));
}

__device__ __forceinline__ float waveSum(float v)
{
  v += dpp_mv<0x111>(v, 0.0f);
  v += dpp_mv<0x112>(v, 0.0f);
  v += dpp_mv<0x114>(v, 0.0f);
  v += dpp_mv<0x118>(v, 0.0f);
  v += dpp_mv<0x142>(v, 0.0f);
  v += dpp_mv<0x143>(v, 0.0f);
  return __int_as_float(__builtin_amdgcn_readlane(__float_as_int(v), 63));
}

// ---------------- Fused kernel: scan (wave 0) + rows (16 waves) -------------
// Phase 1 (R6/R7-validated algebra): v = 0.1*cur + lnb = D + b*A lazily;
// avacc = sum(Pk*khi), Pk = step1*(101-k)/100; beta = 10*(b*SP - avacc);
// w = 0.1*beta + lnb. loss: analytically 0 (R6/R7-validated).
// R8: per-iter scalars precomputed at init; state reads software-pipelined
// one iteration ahead (same-wave DS ordering makes the RAW safe).
__global__ __launch_bounds__(1024) void kern_fused(
    const float *__restrict__ normed, const float *__restrict__ pts,
    float *__restrict__ out)
{
  const int s = blockIdx.x;
  const int t = threadIdx.x;
  const int v = t >> 6;            // wave 0..15
  const int L = t & 63;

  __shared__ float2 dav[MDIM];     // 32 KB: (D, avacc), swizzled
  __shared__ float  barr[MDIM];    // 16 KB: b, becomes w[] after phase 1
  __shared__ float2 pts2[NPTS];    // 4 KB
  __shared__ float4 cstA[NIT + 4]; // (ux, uy, step1, Pk) per iter
  __shared__ int2   cstB[NIT + 4]; // (r0, c0) per iter
  __shared__ float  wdred[16];

  // ---- init (all 16 waves; wave v owns grid rows 4v..4v+3) ----
  #pragma unroll
  for (int l = 0; l < 4; ++l) {
    const int r = 4 * v + l;
    const float bv = normed[s * MDIM + r * 64 + L];
    const int idx = swz(r, L);
    dav[idx]  = make_float2(__logf(bv), 0.0f);   // v0 = lnb
    barr[idx] = bv;
  }
  if (t < NPTS) pts2[t] = ((const float2 *)pts)[s * NPTS + t];
  // per-iteration constants (bit-identical formulas, hoisted out of the loop)
  if (t < NIT + 4) {
    const int kk = t < NIT ? t : (NIT - 1);
    const int idx = rand_idx(s * NIT + kk);
    const float2 p = ((const float2 *)pts)[s * NPTS + idx];
    const int rn = (int)floorf((p.y - 4.0f) * 0.125f + 0.5f);
    const int cn = (int)floorf((p.x - 4.0f) * 0.125f + 0.5f);
    int r0 = rn - 7; r0 = r0 < 0 ? 0 : (r0 > R0MAX ? R0MAX : r0);
    int c0 = cn - 7; c0 = c0 < 0 ? 0 : (c0 > R0MAX ? R0MAX : c0);
    const float kf    = (float)(kk + 1);
    const float step1 = 512.0f * __builtin_amdgcn_rsqf(kf);   // 0.1*lr/sqrt(k)
    const float Pk    = step1 * (0.01f * (101.0f - kf));
    cstA[t] = make_float4(p.x - (float)(8 * c0 + 4),
                          p.y - (float)(8 * r0 + 4), step1, Pk);
    cstB[t] = make_int2(r0, c0);
  }
  __syncthreads();

  const int rbase = L >> 4;        // 0..3 (window row within quad)
  const int cbase = L & 15;        // window col
  const float fc8 = (float)(8 * cbase);
  const float fr8 = (float)(8 * rbase);

  // ---- phase 1: 100-iter ASGD scan, wave 0 only (others wait) ----
  if (v == 0) {
    float A = 0.0f, SP = 0.0f;
    // preload iter 0: constants + state (pipelined pattern)
    float4 cA = cstA[0];
    int2   cB = cstB[0];
    int j0 = swz(cB.x + rbase, cB.y + cbase);
    float2 c0v = dav[j0      ]; float b0v = barr[j0      ];
    float2 c1v = dav[j0 + 256]; float b1v = barr[j0 + 256];
    float2 c2v = dav[j0 + 512]; float b2v = barr[j0 + 512];
    float2 c3v = dav[j0 + 768]; float b3v = barr[j0 + 768];

    for (int k = 0; k < NIT; ++k) {
      // prefetch next-iter constants (independent; latency hidden under chain)
      const float4 cAn = cstA[k + 1];
      const int2   cBn = cstB[k + 1];

      const float dx  = cA.x - fc8;       // x - (8*(c0+cbase)+4)
      const float dxx = dx * dx;
      const float ty  = cA.y - fr8;       // dy_q = ty - 32q
      float z0 = fmaf(fmaf(ty,          ty,          dxx), -0.1f, fmaf(b0v, A, c0v.x));
      float z1 = fmaf(fmaf(ty - 32.0f, ty - 32.0f, dxx), -0.1f, fmaf(b1v, A, c1v.x));
      float z2 = fmaf(fmaf(ty - 64.0f, ty - 64.0f, dxx), -0.1f, fmaf(b2v, A, c2v.x));
      float z3 = fmaf(fmaf(ty - 96.0f, ty - 96.0f, dxx), -0.1f, fmaf(b3v, A, c3v.x));

      const float m = waveMax(fmaxf(fmaxf(z0, z1), fmaxf(z2, z3)));
      const float e0 = __expf(z0 - m), e1 = __expf(z1 - m);
      const float e2 = __expf(z2 - m), e3 = __expf(z3 - m);
      const float S    = waveSum((e0 + e1) + (e2 + e3));   // >= 1
      const float invS = __builtin_amdgcn_rcpf(S);
      const float cD = cA.z * invS, cAv = cA.w * invS;

      c0v.x = fmaf(-cD, e0, c0v.x); c0v.y = fmaf(cAv, e0, c0v.y);
      c1v.x = fmaf(-cD, e1, c1v.x); c1v.y = fmaf(cAv, e1, c1v.y);
      c2v.x = fmaf(-cD, e2, c2v.x); c2v.y = fmaf(cAv, e2, c2v.y);
      c3v.x = fmaf(-cD, e3, c3v.x); c3v.y = fmaf(cAv, e3, c3v.y);
      dav[j0      ] = c0v;
      dav[j0 + 256] = c1v;
      dav[j0 + 512] = c2v;
      dav[j0 + 768] = c3v;

      A += cA.z;
      SP += cA.w;

      // rotate + issue next-iter state reads AFTER the writes (same-wave DS
      // ordering guarantees RAW; latency overlaps loop-back + z-prep)
      cA = cAn; cB = cBn;
      j0 = swz(cB.x + rbase, cB.y + cbase);
      c0v = dav[j0      ]; b0v = barr[j0      ];
      c1v = dav[j0 + 256]; b1v = barr[j0 + 256];
      c2v = dav[j0 + 512]; b2v = barr[j0 + 512];
      c3v = dav[j0 + 768]; b3v = barr[j0 + 768];
    }

    // epilogue: overwrite barr with w[] (in-wave DS order); ot partial
    float p_ot = 0.0f;
    for (int r = 0; r < 64; ++r) {
      const int idx = swz(r, L);
      const float2 cd = dav[idx];
      const float bb  = barr[idx];
      const float tt  = fmaf(bb, SP, -cd.y);     // 0.1*beta
      barr[idx] = tt + __logf(bb);               // w = 0.1*beta + lnb
      p_ot = fmaf(bb, 10.0f * tt, p_ot);
    }
    const float ot = waveSum(p_ot);
    if (L == 0) atomicAdd(&out[2], ot);          // 16 blocks: no contention
  }
  __syncthreads();                               // barr now holds w[]

  // ---- phase 2: windowed per-point logsumexp + wd (all 16 waves) ----
  float wdacc = 0.0f;
  for (int pi = 0; pi < 32; ++pi) {
    const int p = 32 * v + pi;
    const float2 pt = pts2[p];                   // LDS broadcast
    const float x = pt.x, y = pt.y;
    const int rn = (int)floorf((y - 4.0f) * 0.125f + 0.5f);
    const int cn = (int)floorf((x - 4.0f) * 0.125f + 0.5f);
    int r0 = rn - 7; r0 = r0 < 0 ? 0 : (r0 > R0MAX ? R0MAX : r0);
    int c0 = cn - 7; c0 = c0 < 0 ? 0 : (c0 > R0MAX ? R0MAX : c0);
    const int rl = r0 + rbase;
    const int cl = c0 + cbase;
    const int j0 = swz(rl, cl);

    const float dx  = x - (float)(8 * cl + 4);
    const float dxx = dx * dx;
    const float ty  = y - (float)(8 * rl + 4);
    float z[4], q2[4];
    #pragma unroll
    for (int q = 0; q < 4; ++q) {
      const float wv = barr[j0 + 256 * q];
      const float dy = ty - (float)(32 * q);
      q2[q] = fmaf(dy, dy, dxx);
      z[q]  = fmaf(q2[q], -0.1f, wv);
    }
    const float m = waveMax(fmaxf(fmaxf(z[0], z[1]), fmaxf(z[2], z[3])));
    float pe = 0.0f, pq = 0.0f;
    #pragma unroll
    for (int q = 0; q < 4; ++q) {
      const float e = __expf(z[q] - m);
      pe += e;
      pq = fmaf(e, q2[q], pq);
    }
    pe = waveSum(pe);
    pq = waveSum(pq);
    wdacc += pq / pe;                            // alpha shift cancels exactly
  }
  if (L == 0) wdred[v] = wdacc;
  __syncthreads();
  if (t == 0) {
    float wd = 0.0f;
    #pragma unroll
    for (int i = 0; i < 16; ++i) wd += wdred[i];
    atomicAdd(&out[1], wd * (1.0f / 512.0f));
    // out[0] (loss): analytically exact 0; memset provides it.
  }
}

extern "C" void kernel_launch(void* const* d_in, const int* in_sizes, int n_in,
                              void* d_out, int out_size, void* d_ws, size_t ws_size,
                              hipStream_t stream)
{
  (void)in_sizes; (void)n_in; (void)out_size; (void)d_ws; (void)ws_size;
  const float *normed = (const float *)d_in[0];
  const float *pts    = (const float *)d_in[2];
  float *out = (float *)d_out;

  hipMemsetAsync(out, 0, 3 * sizeof(float), stream);
  kern_fused<<<dim3(NSAMP), dim3(1024), 0, stream>>>(normed, pts, out);
}